// Round 4
// baseline (267.897 us; speedup 1.0000x reference)
//
#include <hip/hip_runtime.h>
#include <stdint.h>

// ---------------------------------------------------------------------------
// BitAttention round 4:
//   - flash_attn v4: unpaired grid (16,64) longest-first -> 3 blocks/CU,
//     exp2-domain softmax (bare v_exp_f32), dbuf K/V, defer-max, lazy l
//   - prep_all: sign+|w| for 4 weights AND x->bf16 in one 1152-block kernel
//   - GEMMs unchanged (m97-structure 128^2, documented ceiling)
// ws layout (bytes):
//   [0,5120)    double partials[640]
//   [6144,6304) float tabs[40]: [0..23] qkv col-block scales, [24..39] o
//   [8192,...)  xb(16M) wqkvs(12M) wos(8M) qkvb(24M) ao(16M)
// ---------------------------------------------------------------------------

#define D_MODEL 2048
#define S_LEN   2048
#define BATCH   2
#define NKV     8
#define HD      64
#define MROWS   (BATCH * S_LEN)   // 4096
#define NQKV    3072              // 2048 Q + 512 K + 512 V
#define LDQKV   3072

typedef unsigned short u16;
typedef __bf16 bf16x8 __attribute__((ext_vector_type(8)));
typedef float  f32x4  __attribute__((ext_vector_type(4)));

__device__ __forceinline__ u16 f2bf(float f) {
  union { float f; unsigned u; } v; v.f = f;
  unsigned r = v.u + 0x7FFFu + ((v.u >> 16) & 1u);   // RNE
  return (u16)(r >> 16);
}

__device__ __forceinline__ u16 f2bf_trunc(float f) {
  union { float f; unsigned u; } v; v.f = f;
  return (u16)(v.u >> 16);
}

__device__ __forceinline__ float exp2_fast(float x) {
  float r; asm("v_exp_f32 %0, %1" : "=v"(r) : "v"(x)); return r;
}

__device__ __forceinline__ void lds_load16(u16* lds, const u16* g) {
  __builtin_amdgcn_global_load_lds(
      (const __attribute__((address_space(1))) void*)g,
      (__attribute__((address_space(3))) void*)lds, 16, 0, 0);
}

// ---------------- fused prep: weight sign+|w| partials, x->bf16 ----------------
// grid 1152: [0,256)=wq [256,320)=wk [320,384)=wv [384,640)=wo [640,1152)=x
__global__ void prep_all(const float* __restrict__ wq, const float* __restrict__ wk,
                         const float* __restrict__ wv, const float* __restrict__ wo,
                         const float* __restrict__ x,
                         u16* __restrict__ wqkvs, u16* __restrict__ wos,
                         u16* __restrict__ xb, double* __restrict__ partials) {
  const int bid = blockIdx.x;
  const float* src; u16* dst; int n4, rb, nb; bool sgn = true;
  if (bid < 256)      { src = wq; dst = wqkvs;                  n4 = 1048576; rb = bid;       nb = 256; }
  else if (bid < 320) { src = wk; dst = wqkvs + 2048 * D_MODEL; n4 = 262144;  rb = bid - 256; nb = 64;  }
  else if (bid < 384) { src = wv; dst = wqkvs + 2560 * D_MODEL; n4 = 262144;  rb = bid - 320; nb = 64;  }
  else if (bid < 640) { src = wo; dst = wos;                    n4 = 1048576; rb = bid - 384; nb = 256; }
  else                { src = x;  dst = xb;                     n4 = 2097152; rb = bid - 640; nb = 512; sgn = false; }

  if (sgn) {
    double s = 0.0;
    for (int i = rb * 256 + threadIdx.x; i < n4; i += nb * 256) {
      float4 v = reinterpret_cast<const float4*>(src)[i];
      ushort4 o;
      o.x = v.x > 0.f ? 0x3F80 : (v.x < 0.f ? 0xBF80 : 0);
      o.y = v.y > 0.f ? 0x3F80 : (v.y < 0.f ? 0xBF80 : 0);
      o.z = v.z > 0.f ? 0x3F80 : (v.z < 0.f ? 0xBF80 : 0);
      o.w = v.w > 0.f ? 0x3F80 : (v.w < 0.f ? 0xBF80 : 0);
      reinterpret_cast<ushort4*>(dst)[i] = o;
      s += (double)fabsf(v.x) + (double)fabsf(v.y) +
           (double)fabsf(v.z) + (double)fabsf(v.w);
    }
    __shared__ double sm[256];
    sm[threadIdx.x] = s;
    __syncthreads();
    for (int off = 128; off > 0; off >>= 1) {
      if (threadIdx.x < off) sm[threadIdx.x] += sm[threadIdx.x + off];
      __syncthreads();
    }
    if (threadIdx.x == 0) partials[bid] = sm[0];
  } else {
    for (int i = rb * 256 + threadIdx.x; i < n4; i += nb * 256) {
      float4 v = reinterpret_cast<const float4*>(src)[i];
      ushort4 o;
      o.x = f2bf(v.x); o.y = f2bf(v.y); o.z = f2bf(v.z); o.w = f2bf(v.w);
      reinterpret_cast<ushort4*>(dst)[i] = o;
    }
  }
}

__global__ void finalize_scales(const double* __restrict__ partials,
                                float* __restrict__ tabs) {
  if (threadIdx.x == 0 && blockIdx.x == 0) {
    const int beg[4] = {0, 256, 320, 384};
    const int end[4] = {256, 320, 384, 640};
    const double counts[4] = {4194304.0, 1048576.0, 1048576.0, 4194304.0};
    float sc[4];
    for (int w = 0; w < 4; ++w) {
      double s = 0.0;
      for (int i = beg[w]; i < end[w]; ++i) s += partials[i];
      sc[w] = fmaxf((float)(s / counts[w]), 1e-5f);
    }
    for (int i = 0; i < 24; ++i) tabs[i] = (i < 16) ? sc[0] : (i < 20 ? sc[1] : sc[2]);
    for (int i = 0; i < 16; ++i) tabs[24 + i] = sc[3];
  }
}

// ---------------- GEMM: C[m,n] = tab[bx] * sum_k A[m,k]*Bt[n,k] ----------------
template <int OUT_BF16>
__global__ __launch_bounds__(256, 2) void gemm_bt(
    const u16* __restrict__ A, const u16* __restrict__ Bt, void* __restrict__ Cv,
    const float* __restrict__ tab, int M, int N, int K) {
  __shared__ u16 lA[128 * 64];
  __shared__ u16 lB[128 * 64];
  const int tid = threadIdx.x;
  const int lane = tid & 63, wave = tid >> 6;
  const int lo = lane & 15, hi = lane >> 4;
  const int m0 = blockIdx.y * 128, n0 = blockIdx.x * 128;
  const int wr = (wave >> 1) * 64, wc = (wave & 1) * 64;

  f32x4 acc[4][4] = {};

  for (int k0 = 0; k0 < K; k0 += 64) {
#pragma unroll
    for (int it = 0; it < 4; ++it) {
      const int c = it * 256 + wave * 64 + lane;
      const int row = c >> 3, kc = (c & 7) << 3;
      lds_load16(&lA[(it * 256 + wave * 64) * 8], &A[(size_t)(m0 + row) * K + k0 + kc]);
      lds_load16(&lB[(it * 256 + wave * 64) * 8], &Bt[(size_t)(n0 + row) * K + k0 + kc]);
    }
    __syncthreads();
#pragma unroll
    for (int kk = 0; kk < 2; ++kk) {
      bf16x8 af[4], bfr[4];
#pragma unroll
      for (int i = 0; i < 4; ++i)
        af[i] = *reinterpret_cast<const bf16x8*>(&lA[(wr + i * 16 + lo) * 64 + kk * 32 + hi * 8]);
#pragma unroll
      for (int i = 0; i < 4; ++i)
        bfr[i] = *reinterpret_cast<const bf16x8*>(&lB[(wc + i * 16 + lo) * 64 + kk * 32 + hi * 8]);
#pragma unroll
      for (int mi = 0; mi < 4; ++mi)
#pragma unroll
        for (int ni = 0; ni < 4; ++ni)
          acc[mi][ni] = __builtin_amdgcn_mfma_f32_16x16x32_bf16(af[mi], bfr[ni], acc[mi][ni], 0, 0, 0);
    }
    __syncthreads();
  }

  const float scale = tab[blockIdx.x];
#pragma unroll
  for (int mi = 0; mi < 4; ++mi) {
#pragma unroll
    for (int ni = 0; ni < 4; ++ni) {
#pragma unroll
      for (int r = 0; r < 4; ++r) {
        const int row = m0 + wr + mi * 16 + hi * 4 + r;
        const int col = n0 + wc + ni * 16 + lo;
        const float v = acc[mi][ni][r] * scale;
        if (OUT_BF16)
          reinterpret_cast<u16*>(Cv)[(size_t)row * N + col] = f2bf(v);
        else
          reinterpret_cast<float*>(Cv)[(size_t)row * N + col] = v;
      }
    }
  }
}

// ---------------- flash attention v4 (GQA, causal, longest-first) ----------------
__device__ __forceinline__ void stage_k(u16* dst, const u16* Kg, int rowbase,
                                        int tid, int wave) {
#pragma unroll
  for (int it = 0; it < 2; ++it) {
    const int c = it * 256 + tid;
    const int row = c >> 3;
    const int ch = (c & 7) ^ (row & 7);   // pre-swizzled source (rule #21)
    lds_load16(dst + (it * 256 + wave * 64) * 8,
               Kg + (size_t)(rowbase + row) * LDQKV + ch * 8);
  }
}

__device__ __forceinline__ void load_v(const u16* Vg, int rowbase, int lane, int wave,
                                       uint4& a, uint4& b) {
  const size_t vr = (size_t)(rowbase + lane) * LDQKV;
  a = *reinterpret_cast<const uint4*>(Vg + vr + wave * 8);
  b = *reinterpret_cast<const uint4*>(Vg + vr + (4 + wave) * 8);
}

__device__ __forceinline__ void write_v(u16* lVt, int lane, int wave,
                                        const uint4& a, const uint4& b) {
  const unsigned* pw0 = reinterpret_cast<const unsigned*>(&a);
  const unsigned* pw1 = reinterpret_cast<const unsigned*>(&b);
#pragma unroll
  for (int j = 0; j < 4; ++j) {
    const int d0 = wave * 8 + 2 * j;
    lVt[(d0 + 0) * 72 + lane] = (u16)(pw0[j] & 0xffffu);
    lVt[(d0 + 1) * 72 + lane] = (u16)(pw0[j] >> 16);
    const int d1 = (4 + wave) * 8 + 2 * j;
    lVt[(d1 + 0) * 72 + lane] = (u16)(pw1[j] & 0xffffu);
    lVt[(d1 + 1) * 72 + lane] = (u16)(pw1[j] >> 16);
  }
}

#define SM_LOG2E 0.180336880f   // (1/sqrt(64)) * log2(e)
#define THR_LOG2 11.5415603f    // 8 * log2(e)

__global__ __launch_bounds__(256, 3) void flash_attn(
    const u16* __restrict__ QKV, u16* __restrict__ Og) {
  __shared__ u16 lK[2][64 * 64];    // XOR-swizzled chunks
  __shared__ u16 lVt[2][64 * 72];   // [d][t]
  __shared__ u16 lP[4][32 * 72];    // per-wave P[q][t]

  const int tid = threadIdx.x;
  const int lane = tid & 63, wave = tid >> 6;
  const int lo = lane & 15, hi = lane >> 4;
  const int hy = blockIdx.y;
  const int b = hy >> 5, h = hy & 31, kv = h >> 2;
  const int brow = b * S_LEN;
  const u16* Q  = QKV + h * HD;
  const u16* Kg = QKV + 2048 + kv * HD;
  const u16* Vg = QKV + 2560 + kv * HD;
  const int swl = (lo & 7) << 3;

  const int qt = 15 - (int)blockIdx.x;   // longest-first dispatch
  const int q0 = qt * 128;
  const int q0w = q0 + wave * 32;
  const int nt = 2 * qt + 2;

  // Q fragments resident for the whole kernel
  bf16x8 qf[2][2];
#pragma unroll
  for (int mi = 0; mi < 2; ++mi) {
    const size_t qr = (size_t)(brow + q0w + mi * 16 + lo) * LDQKV;
#pragma unroll
    for (int kk = 0; kk < 2; ++kk)
      qf[mi][kk] = *reinterpret_cast<const bf16x8*>(&Q[qr + kk * 32 + hi * 8]);
  }

  f32x4 oacc[2][4] = {};
  float m_run[2][4], l_lane[2][4];
#pragma unroll
  for (int mi = 0; mi < 2; ++mi)
#pragma unroll
    for (int r = 0; r < 4; ++r) { m_run[mi][r] = -1e30f; l_lane[mi][r] = 0.f; }

  // prologue: stage tile 0 into buffer 0
  stage_k(lK[0], Kg, brow, tid, wave);
  {
    uint4 va, vb;
    load_v(Vg, brow, lane, wave, va, vb);
    write_v(lVt[0], lane, wave, va, vb);
  }
  __syncthreads();

#pragma unroll 1
  for (int ti = 0; ti < nt; ++ti) {
    const int t0 = ti * 64;
    const int cur = ti & 1;
    u16* lKc = (u16*)lK[cur];
    u16* lVc = (u16*)lVt[cur];

    // ---- S = Q K^T ----
    f32x4 sacc[2][4] = {};
    __builtin_amdgcn_s_setprio(1);
#pragma unroll
    for (int kk = 0; kk < 2; ++kk) {
#pragma unroll
      for (int nf = 0; nf < 4; ++nf) {
        bf16x8 kf = *reinterpret_cast<const bf16x8*>(
            &lKc[(nf * 16 + lo) * 64 + ((kk * 32 + hi * 8) ^ swl)]);
#pragma unroll
        for (int mi = 0; mi < 2; ++mi)
          sacc[mi][nf] = __builtin_amdgcn_mfma_f32_16x16x32_bf16(
              qf[mi][kk], kf, sacc[mi][nf], 0, 0, 0);
      }
    }
    __builtin_amdgcn_s_setprio(0);

    // ---- prefetch next tile (K direct to LDS, V to regs) ----
    uint4 van, vbn;
    const bool has_next = (ti + 1 < nt);
    if (has_next) {
      stage_k(lK[cur ^ 1], Kg, brow + t0 + 64, tid, wave);
      load_v(Vg, brow + t0 + 64, lane, wave, van, vbn);
    }

    // ---- mask + scale (log2 domain) + local max ----
    const bool full = (t0 + 64 <= q0);
    float p[2][4][4];
    float mtl[2][4];
    bool okl = true;
#pragma unroll
    for (int mi = 0; mi < 2; ++mi) {
      float mt0 = -1e30f, mt1 = -1e30f, mt2 = -1e30f, mt3 = -1e30f;
#pragma unroll
      for (int nf = 0; nf < 4; ++nf) {
        const int tg = t0 + nf * 16 + lo;
#pragma unroll
        for (int r = 0; r < 4; ++r) {
          float s = sacc[mi][nf][r] * SM_LOG2E;
          if (!full) {
            const int qg = q0w + mi * 16 + hi * 4 + r;
            if (tg > qg) s = -1e30f;
          }
          p[mi][nf][r] = s;
          if (r == 0) mt0 = fmaxf(mt0, s);
          if (r == 1) mt1 = fmaxf(mt1, s);
          if (r == 2) mt2 = fmaxf(mt2, s);
          if (r == 3) mt3 = fmaxf(mt3, s);
        }
      }
      mtl[mi][0] = mt0; mtl[mi][1] = mt1; mtl[mi][2] = mt2; mtl[mi][3] = mt3;
#pragma unroll
      for (int r = 0; r < 4; ++r) okl = okl && (mtl[mi][r] <= m_run[mi][r] + THR_LOG2);
    }

    // ---- defer-max: full rescale only when a row max grew (T13) ----
    if (!__all((int)okl)) {
#pragma unroll
      for (int mi = 0; mi < 2; ++mi) {
#pragma unroll
        for (int r = 0; r < 4; ++r) {
          float v = mtl[mi][r];
          v = fmaxf(v, __shfl_xor(v, 1));
          v = fmaxf(v, __shfl_xor(v, 2));
          v = fmaxf(v, __shfl_xor(v, 4));
          v = fmaxf(v, __shfl_xor(v, 8));
          const float mn = fmaxf(m_run[mi][r], v);
          const float alpha = exp2_fast(m_run[mi][r] - mn);
          m_run[mi][r] = mn;
          l_lane[mi][r] *= alpha;
#pragma unroll
          for (int nf = 0; nf < 4; ++nf) oacc[mi][nf][r] *= alpha;
        }
      }
    }

    // ---- exp2 + P write (trunc bf16) + lane-partial l ----
#pragma unroll
    for (int mi = 0; mi < 2; ++mi) {
#pragma unroll
      for (int r = 0; r < 4; ++r) {
        float rs = 0.f;
#pragma unroll
        for (int nf = 0; nf < 4; ++nf) {
          const float e = exp2_fast(p[mi][nf][r] - m_run[mi][r]);
          rs += e;
          lP[wave][(mi * 16 + hi * 4 + r) * 72 + nf * 16 + lo] = f2bf_trunc(e);
        }
        l_lane[mi][r] += rs;
      }
    }

    // ---- V for next tile into other buffer (no barrier needed) ----
    if (has_next) write_v(lVt[cur ^ 1], lane, wave, van, vbn);

    // ---- O += P V ----
    __builtin_amdgcn_s_setprio(1);
#pragma unroll
    for (int kk = 0; kk < 2; ++kk) {
      bf16x8 pf[2];
#pragma unroll
      for (int mi = 0; mi < 2; ++mi)
        pf[mi] = *reinterpret_cast<const bf16x8*>(
            &lP[wave][(mi * 16 + lo) * 72 + kk * 32 + hi * 8]);
#pragma unroll
      for (int nf = 0; nf < 4; ++nf) {
        bf16x8 vf = *reinterpret_cast<const bf16x8*>(
            &lVc[(nf * 16 + lo) * 72 + kk * 32 + hi * 8]);
#pragma unroll
        for (int mi = 0; mi < 2; ++mi)
          oacc[mi][nf] = __builtin_amdgcn_mfma_f32_16x16x32_bf16(
              pf[mi], vf, oacc[mi][nf], 0, 0, 0);
      }
    }
    __builtin_amdgcn_s_setprio(0);
    __syncthreads();   // all reads of cur done before it becomes the stage target
  }

  // ---- epilogue: reduce lane-partial l across the 16-lane group, store ----
#pragma unroll
  for (int mi = 0; mi < 2; ++mi) {
    float inv[4];
#pragma unroll
    for (int r = 0; r < 4; ++r) {
      float ls = l_lane[mi][r];
      ls += __shfl_xor(ls, 1);
      ls += __shfl_xor(ls, 2);
      ls += __shfl_xor(ls, 4);
      ls += __shfl_xor(ls, 8);
      inv[r] = 1.f / ls;
    }
#pragma unroll
    for (int nf = 0; nf < 4; ++nf)
#pragma unroll
      for (int r = 0; r < 4; ++r)
        Og[(size_t)(brow + q0w + mi * 16 + hi * 4 + r) * D_MODEL +
           h * HD + nf * 16 + lo] = f2bf(oacc[mi][nf][r] * inv[r]);
  }
}

// ---------------- launcher ----------------
extern "C" void kernel_launch(void* const* d_in, const int* in_sizes, int n_in,
                              void* d_out, int out_size, void* d_ws, size_t ws_size,
                              hipStream_t stream) {
  (void)in_sizes; (void)n_in; (void)out_size; (void)ws_size;
  const float* x  = (const float*)d_in[0];
  const float* wq = (const float*)d_in[1];
  const float* wk = (const float*)d_in[2];
  const float* wv = (const float*)d_in[3];
  const float* wo = (const float*)d_in[4];
  float* out = (float*)d_out;
  char* ws = (char*)d_ws;

  double* partials = (double*)ws;            // 640 * 8 B
  float* tabs = (float*)(ws + 6144);         // 40 floats
  size_t off = 8192;
  u16* xb    = (u16*)(ws + off); off += (size_t)MROWS * D_MODEL * 2;
  u16* wqkvs = (u16*)(ws + off); off += (size_t)NQKV * D_MODEL * 2;
  u16* wos   = (u16*)(ws + off); off += (size_t)D_MODEL * D_MODEL * 2;
  u16* qkvb  = (u16*)(ws + off); off += (size_t)MROWS * NQKV * 2;
  u16* ao    = (u16*)(ws + off); off += (size_t)MROWS * D_MODEL * 2;

  // 1. fused prep: weight signs + |w| partials + x->bf16
  prep_all<<<1152, 256, 0, stream>>>(wq, wk, wv, wo, x, wqkvs, wos, xb, partials);
  finalize_scales<<<1, 64, 0, stream>>>(partials, tabs);

  // 2. fused QKV projection (N = 3072)
  gemm_bt<1><<<dim3(NQKV / 128, MROWS / 128), 256, 0, stream>>>(
      xb, wqkvs, qkvb, tabs, MROWS, NQKV, D_MODEL);

  // 3. GQA causal flash attention (longest-first, 3 blocks/CU)
  flash_attn<<<dim3(16, 64), 256, 0, stream>>>(qkvb, ao);

  // 4. output projection (f32 out)
  gemm_bt<0><<<dim3(D_MODEL / 128, MROWS / 128), 256, 0, stream>>>(
      ao, wos, out, tabs + 24, MROWS, D_MODEL, D_MODEL);
}

// Round 5
// 214.175 us; speedup vs baseline: 1.2508x; 1.2508x over previous
//
#include <hip/hip_runtime.h>
#include <stdint.h>

// ---------------------------------------------------------------------------
// BitAttention round 5 (consolidation):
//   - flash_attn: ROUND-3 paired structure restored (grid (8,64), constant
//     34 tile-units/block, 2 blocks/CU, dbuf K/V, defer-max, lazy l)
//     + exp2-domain softmax with sm_scale*log2e FOLDED INTO Q (GEMM epilogue)
//   - prep_all: weights sign+|w| and x->bf16 in one kernel (round-4, kept)
//   - GEMMs unchanged (m97-structure 128^2)
// ws layout (bytes):
//   [0,5120)    double partials[640]
//   [6144,6304) float tabs[40]: [0..23] qkv col-block scales, [24..39] o
//   [8192,...)  xb(16M) wqkvs(12M) wos(8M) qkvb(24M) ao(16M)
// ---------------------------------------------------------------------------

#define D_MODEL 2048
#define S_LEN   2048
#define BATCH   2
#define NKV     8
#define HD      64
#define MROWS   (BATCH * S_LEN)   // 4096
#define NQKV    3072              // 2048 Q + 512 K + 512 V
#define LDQKV   3072

typedef unsigned short u16;
typedef __bf16 bf16x8 __attribute__((ext_vector_type(8)));
typedef float  f32x4  __attribute__((ext_vector_type(4)));

__device__ __forceinline__ u16 f2bf(float f) {
  union { float f; unsigned u; } v; v.f = f;
  unsigned r = v.u + 0x7FFFu + ((v.u >> 16) & 1u);   // RNE
  return (u16)(r >> 16);
}

__device__ __forceinline__ u16 f2bf_trunc(float f) {
  union { float f; unsigned u; } v; v.f = f;
  return (u16)(v.u >> 16);
}

__device__ __forceinline__ float exp2_fast(float x) {
  float r; asm("v_exp_f32 %0, %1" : "=v"(r) : "v"(x)); return r;
}

__device__ __forceinline__ void lds_load16(u16* lds, const u16* g) {
  __builtin_amdgcn_global_load_lds(
      (const __attribute__((address_space(1))) void*)g,
      (__attribute__((address_space(3))) void*)lds, 16, 0, 0);
}

#define SM_LOG2E 0.180336880f   // (1/sqrt(64)) * log2(e); folded into Q storage
#define THR_LOG2 11.5415603f    // 8 * log2(e)

// ---------------- fused prep: weight sign+|w| partials, x->bf16 ----------------
// grid 1152: [0,256)=wq [256,320)=wk [320,384)=wv [384,640)=wo [640,1152)=x
__global__ void prep_all(const float* __restrict__ wq, const float* __restrict__ wk,
                         const float* __restrict__ wv, const float* __restrict__ wo,
                         const float* __restrict__ x,
                         u16* __restrict__ wqkvs, u16* __restrict__ wos,
                         u16* __restrict__ xb, double* __restrict__ partials) {
  const int bid = blockIdx.x;
  const float* src; u16* dst; int n4, rb, nb; bool sgn = true;
  if (bid < 256)      { src = wq; dst = wqkvs;                  n4 = 1048576; rb = bid;       nb = 256; }
  else if (bid < 320) { src = wk; dst = wqkvs + 2048 * D_MODEL; n4 = 262144;  rb = bid - 256; nb = 64;  }
  else if (bid < 384) { src = wv; dst = wqkvs + 2560 * D_MODEL; n4 = 262144;  rb = bid - 320; nb = 64;  }
  else if (bid < 640) { src = wo; dst = wos;                    n4 = 1048576; rb = bid - 384; nb = 256; }
  else                { src = x;  dst = xb;                     n4 = 2097152; rb = bid - 640; nb = 512; sgn = false; }

  if (sgn) {
    double s = 0.0;
    for (int i = rb * 256 + threadIdx.x; i < n4; i += nb * 256) {
      float4 v = reinterpret_cast<const float4*>(src)[i];
      ushort4 o;
      o.x = v.x > 0.f ? 0x3F80 : (v.x < 0.f ? 0xBF80 : 0);
      o.y = v.y > 0.f ? 0x3F80 : (v.y < 0.f ? 0xBF80 : 0);
      o.z = v.z > 0.f ? 0x3F80 : (v.z < 0.f ? 0xBF80 : 0);
      o.w = v.w > 0.f ? 0x3F80 : (v.w < 0.f ? 0xBF80 : 0);
      reinterpret_cast<ushort4*>(dst)[i] = o;
      s += (double)fabsf(v.x) + (double)fabsf(v.y) +
           (double)fabsf(v.z) + (double)fabsf(v.w);
    }
    __shared__ double sm[256];
    sm[threadIdx.x] = s;
    __syncthreads();
    for (int off = 128; off > 0; off >>= 1) {
      if (threadIdx.x < off) sm[threadIdx.x] += sm[threadIdx.x + off];
      __syncthreads();
    }
    if (threadIdx.x == 0) partials[bid] = sm[0];
  } else {
    for (int i = rb * 256 + threadIdx.x; i < n4; i += nb * 256) {
      float4 v = reinterpret_cast<const float4*>(src)[i];
      ushort4 o;
      o.x = f2bf(v.x); o.y = f2bf(v.y); o.z = f2bf(v.z); o.w = f2bf(v.w);
      reinterpret_cast<ushort4*>(dst)[i] = o;
    }
  }
}

__global__ void finalize_scales(const double* __restrict__ partials,
                                float* __restrict__ tabs) {
  if (threadIdx.x == 0 && blockIdx.x == 0) {
    const int beg[4] = {0, 256, 320, 384};
    const int end[4] = {256, 320, 384, 640};
    const double counts[4] = {4194304.0, 1048576.0, 1048576.0, 4194304.0};
    float sc[4];
    for (int w = 0; w < 4; ++w) {
      double s = 0.0;
      for (int i = beg[w]; i < end[w]; ++i) s += partials[i];
      sc[w] = fmaxf((float)(s / counts[w]), 1e-5f);
    }
    // Q columns carry sm_scale*log2e so attention skips the per-element mul.
    for (int i = 0; i < 24; ++i)
      tabs[i] = (i < 16) ? sc[0] * SM_LOG2E : (i < 20 ? sc[1] : sc[2]);
    for (int i = 0; i < 16; ++i) tabs[24 + i] = sc[3];
  }
}

// ---------------- GEMM: C[m,n] = tab[bx] * sum_k A[m,k]*Bt[n,k] ----------------
template <int OUT_BF16>
__global__ __launch_bounds__(256, 2) void gemm_bt(
    const u16* __restrict__ A, const u16* __restrict__ Bt, void* __restrict__ Cv,
    const float* __restrict__ tab, int M, int N, int K) {
  __shared__ u16 lA[128 * 64];
  __shared__ u16 lB[128 * 64];
  const int tid = threadIdx.x;
  const int lane = tid & 63, wave = tid >> 6;
  const int lo = lane & 15, hi = lane >> 4;
  const int m0 = blockIdx.y * 128, n0 = blockIdx.x * 128;
  const int wr = (wave >> 1) * 64, wc = (wave & 1) * 64;

  f32x4 acc[4][4] = {};

  for (int k0 = 0; k0 < K; k0 += 64) {
#pragma unroll
    for (int it = 0; it < 4; ++it) {
      const int c = it * 256 + wave * 64 + lane;
      const int row = c >> 3, kc = (c & 7) << 3;
      lds_load16(&lA[(it * 256 + wave * 64) * 8], &A[(size_t)(m0 + row) * K + k0 + kc]);
      lds_load16(&lB[(it * 256 + wave * 64) * 8], &Bt[(size_t)(n0 + row) * K + k0 + kc]);
    }
    __syncthreads();
#pragma unroll
    for (int kk = 0; kk < 2; ++kk) {
      bf16x8 af[4], bfr[4];
#pragma unroll
      for (int i = 0; i < 4; ++i)
        af[i] = *reinterpret_cast<const bf16x8*>(&lA[(wr + i * 16 + lo) * 64 + kk * 32 + hi * 8]);
#pragma unroll
      for (int i = 0; i < 4; ++i)
        bfr[i] = *reinterpret_cast<const bf16x8*>(&lB[(wc + i * 16 + lo) * 64 + kk * 32 + hi * 8]);
#pragma unroll
      for (int mi = 0; mi < 4; ++mi)
#pragma unroll
        for (int ni = 0; ni < 4; ++ni)
          acc[mi][ni] = __builtin_amdgcn_mfma_f32_16x16x32_bf16(af[mi], bfr[ni], acc[mi][ni], 0, 0, 0);
    }
    __syncthreads();
  }

  const float scale = tab[blockIdx.x];
#pragma unroll
  for (int mi = 0; mi < 4; ++mi) {
#pragma unroll
    for (int ni = 0; ni < 4; ++ni) {
#pragma unroll
      for (int r = 0; r < 4; ++r) {
        const int row = m0 + wr + mi * 16 + hi * 4 + r;
        const int col = n0 + wc + ni * 16 + lo;
        const float v = acc[mi][ni][r] * scale;
        if (OUT_BF16)
          reinterpret_cast<u16*>(Cv)[(size_t)row * N + col] = f2bf(v);
        else
          reinterpret_cast<float*>(Cv)[(size_t)row * N + col] = v;
      }
    }
  }
}

// ---------------- flash attention v5 (GQA, causal, paired/balanced) ----------------
// grid: (8, 64).  blockIdx.y = b*32+h;  block does q-tiles bx and 15-bx.
__device__ __forceinline__ void stage_k(u16* dst, const u16* Kg, int rowbase,
                                        int tid, int wave) {
#pragma unroll
  for (int it = 0; it < 2; ++it) {
    const int c = it * 256 + tid;
    const int row = c >> 3;
    const int ch = (c & 7) ^ (row & 7);   // pre-swizzled source (rule #21)
    lds_load16(dst + (it * 256 + wave * 64) * 8,
               Kg + (size_t)(rowbase + row) * LDQKV + ch * 8);
  }
}

__device__ __forceinline__ void load_v(const u16* Vg, int rowbase, int lane, int wave,
                                       uint4& a, uint4& b) {
  const size_t vr = (size_t)(rowbase + lane) * LDQKV;
  a = *reinterpret_cast<const uint4*>(Vg + vr + wave * 8);
  b = *reinterpret_cast<const uint4*>(Vg + vr + (4 + wave) * 8);
}

__device__ __forceinline__ void write_v(u16* lVt, int lane, int wave,
                                        const uint4& a, const uint4& b) {
  const unsigned* pw0 = reinterpret_cast<const unsigned*>(&a);
  const unsigned* pw1 = reinterpret_cast<const unsigned*>(&b);
#pragma unroll
  for (int j = 0; j < 4; ++j) {
    const int d0 = wave * 8 + 2 * j;
    lVt[(d0 + 0) * 72 + lane] = (u16)(pw0[j] & 0xffffu);
    lVt[(d0 + 1) * 72 + lane] = (u16)(pw0[j] >> 16);
    const int d1 = (4 + wave) * 8 + 2 * j;
    lVt[(d1 + 0) * 72 + lane] = (u16)(pw1[j] & 0xffffu);
    lVt[(d1 + 1) * 72 + lane] = (u16)(pw1[j] >> 16);
  }
}

__global__ __launch_bounds__(256, 2) void flash_attn(
    const u16* __restrict__ QKV, u16* __restrict__ Og) {
  __shared__ u16 lK[2][64 * 64];    // XOR-swizzled chunks
  __shared__ u16 lVt[2][64 * 72];   // [d][t]
  __shared__ u16 lP[4][32 * 72];    // per-wave P[q][t]

  const int tid = threadIdx.x;
  const int lane = tid & 63, wave = tid >> 6;
  const int lo = lane & 15, hi = lane >> 4;
  const int hy = blockIdx.y;
  const int b = hy >> 5, h = hy & 31, kv = h >> 2;
  const int brow = b * S_LEN;
  const u16* Q  = QKV + h * HD;
  const u16* Kg = QKV + 2048 + kv * HD;
  const u16* Vg = QKV + 2560 + kv * HD;
  const int swl = (lo & 7) << 3;

#pragma unroll 1
  for (int pi = 0; pi < 2; ++pi) {
    const int qt = pi == 0 ? (int)blockIdx.x : (15 - (int)blockIdx.x);
    const int q0 = qt * 128;
    const int q0w = q0 + wave * 32;
    const int nt = 2 * qt + 2;

    // Q fragments resident for the pass (Q already carries sm_scale*log2e)
    bf16x8 qf[2][2];
#pragma unroll
    for (int mi = 0; mi < 2; ++mi) {
      const size_t qr = (size_t)(brow + q0w + mi * 16 + lo) * LDQKV;
#pragma unroll
      for (int kk = 0; kk < 2; ++kk)
        qf[mi][kk] = *reinterpret_cast<const bf16x8*>(&Q[qr + kk * 32 + hi * 8]);
    }

    f32x4 oacc[2][4] = {};
    float m_run[2][4], l_lane[2][4];
#pragma unroll
    for (int mi = 0; mi < 2; ++mi)
#pragma unroll
      for (int r = 0; r < 4; ++r) { m_run[mi][r] = -1e30f; l_lane[mi][r] = 0.f; }

    // prologue: stage tile 0 into buffer 0
    stage_k(lK[0], Kg, brow, tid, wave);
    {
      uint4 va, vb;
      load_v(Vg, brow, lane, wave, va, vb);
      write_v(lVt[0], lane, wave, va, vb);
    }
    __syncthreads();

#pragma unroll 1
    for (int ti = 0; ti < nt; ++ti) {
      const int t0 = ti * 64;
      const int cur = ti & 1;
      u16* lKc = (u16*)lK[cur];
      u16* lVc = (u16*)lVt[cur];

      // ---- S = Q K^T  (already in log2 domain via pre-scaled Q) ----
      f32x4 sacc[2][4] = {};
      __builtin_amdgcn_s_setprio(1);
#pragma unroll
      for (int kk = 0; kk < 2; ++kk) {
#pragma unroll
        for (int nf = 0; nf < 4; ++nf) {
          bf16x8 kf = *reinterpret_cast<const bf16x8*>(
              &lKc[(nf * 16 + lo) * 64 + ((kk * 32 + hi * 8) ^ swl)]);
#pragma unroll
          for (int mi = 0; mi < 2; ++mi)
            sacc[mi][nf] = __builtin_amdgcn_mfma_f32_16x16x32_bf16(
                qf[mi][kk], kf, sacc[mi][nf], 0, 0, 0);
        }
      }
      __builtin_amdgcn_s_setprio(0);

      // ---- prefetch next tile (K direct to LDS, V to regs) ----
      uint4 van, vbn;
      const bool has_next = (ti + 1 < nt);
      if (has_next) {
        stage_k(lK[cur ^ 1], Kg, brow + t0 + 64, tid, wave);
        load_v(Vg, brow + t0 + 64, lane, wave, van, vbn);
      }

      // ---- mask + local max (log2 domain) ----
      const bool full = (t0 + 64 <= q0);
      float p[2][4][4];
      float mtl[2][4];
      bool okl = true;
#pragma unroll
      for (int mi = 0; mi < 2; ++mi) {
        float mt0 = -1e30f, mt1 = -1e30f, mt2 = -1e30f, mt3 = -1e30f;
#pragma unroll
        for (int nf = 0; nf < 4; ++nf) {
          const int tg = t0 + nf * 16 + lo;
#pragma unroll
          for (int r = 0; r < 4; ++r) {
            float s = sacc[mi][nf][r];
            if (!full) {
              const int qg = q0w + mi * 16 + hi * 4 + r;
              if (tg > qg) s = -1e30f;
            }
            p[mi][nf][r] = s;
            if (r == 0) mt0 = fmaxf(mt0, s);
            if (r == 1) mt1 = fmaxf(mt1, s);
            if (r == 2) mt2 = fmaxf(mt2, s);
            if (r == 3) mt3 = fmaxf(mt3, s);
          }
        }
        mtl[mi][0] = mt0; mtl[mi][1] = mt1; mtl[mi][2] = mt2; mtl[mi][3] = mt3;
#pragma unroll
        for (int r = 0; r < 4; ++r) okl = okl && (mtl[mi][r] <= m_run[mi][r] + THR_LOG2);
      }

      // ---- defer-max: full rescale only when a row max grew (T13) ----
      if (!__all((int)okl)) {
#pragma unroll
        for (int mi = 0; mi < 2; ++mi) {
#pragma unroll
          for (int r = 0; r < 4; ++r) {
            float v = mtl[mi][r];
            v = fmaxf(v, __shfl_xor(v, 1));
            v = fmaxf(v, __shfl_xor(v, 2));
            v = fmaxf(v, __shfl_xor(v, 4));
            v = fmaxf(v, __shfl_xor(v, 8));
            const float mn = fmaxf(m_run[mi][r], v);
            const float alpha = exp2_fast(m_run[mi][r] - mn);
            m_run[mi][r] = mn;
            l_lane[mi][r] *= alpha;
#pragma unroll
            for (int nf = 0; nf < 4; ++nf) oacc[mi][nf][r] *= alpha;
          }
        }
      }

      // ---- exp2 + P write (trunc bf16) + lane-partial l ----
#pragma unroll
      for (int mi = 0; mi < 2; ++mi) {
#pragma unroll
        for (int r = 0; r < 4; ++r) {
          float rs = 0.f;
#pragma unroll
          for (int nf = 0; nf < 4; ++nf) {
            const float e = exp2_fast(p[mi][nf][r] - m_run[mi][r]);
            rs += e;
            lP[wave][(mi * 16 + hi * 4 + r) * 72 + nf * 16 + lo] = f2bf_trunc(e);
          }
          l_lane[mi][r] += rs;
        }
      }

      // ---- V for next tile into other buffer (no barrier needed) ----
      if (has_next) write_v(lVt[cur ^ 1], lane, wave, van, vbn);

      // ---- O += P V ----
      __builtin_amdgcn_s_setprio(1);
#pragma unroll
      for (int kk = 0; kk < 2; ++kk) {
        bf16x8 pf[2];
#pragma unroll
        for (int mi = 0; mi < 2; ++mi)
          pf[mi] = *reinterpret_cast<const bf16x8*>(
              &lP[wave][(mi * 16 + lo) * 72 + kk * 32 + hi * 8]);
#pragma unroll
        for (int nf = 0; nf < 4; ++nf) {
          bf16x8 vf = *reinterpret_cast<const bf16x8*>(
              &lVc[(nf * 16 + lo) * 72 + kk * 32 + hi * 8]);
#pragma unroll
          for (int mi = 0; mi < 2; ++mi)
            oacc[mi][nf] = __builtin_amdgcn_mfma_f32_16x16x32_bf16(
                pf[mi], vf, oacc[mi][nf], 0, 0, 0);
        }
      }
      __builtin_amdgcn_s_setprio(0);
      __syncthreads();   // all reads of cur done before it becomes the stage target
    }

    // ---- epilogue: reduce lane-partial l across the 16-lane group, store ----
#pragma unroll
    for (int mi = 0; mi < 2; ++mi) {
      float inv[4];
#pragma unroll
      for (int r = 0; r < 4; ++r) {
        float ls = l_lane[mi][r];
        ls += __shfl_xor(ls, 1);
        ls += __shfl_xor(ls, 2);
        ls += __shfl_xor(ls, 4);
        ls += __shfl_xor(ls, 8);
        inv[r] = 1.f / ls;
      }
#pragma unroll
      for (int nf = 0; nf < 4; ++nf)
#pragma unroll
        for (int r = 0; r < 4; ++r)
          Og[(size_t)(brow + q0w + mi * 16 + hi * 4 + r) * D_MODEL +
             h * HD + nf * 16 + lo] = f2bf(oacc[mi][nf][r] * inv[r]);
    }
  }
}

// ---------------- launcher ----------------
extern "C" void kernel_launch(void* const* d_in, const int* in_sizes, int n_in,
                              void* d_out, int out_size, void* d_ws, size_t ws_size,
                              hipStream_t stream) {
  (void)in_sizes; (void)n_in; (void)out_size; (void)ws_size;
  const float* x  = (const float*)d_in[0];
  const float* wq = (const float*)d_in[1];
  const float* wk = (const float*)d_in[2];
  const float* wv = (const float*)d_in[3];
  const float* wo = (const float*)d_in[4];
  float* out = (float*)d_out;
  char* ws = (char*)d_ws;

  double* partials = (double*)ws;            // 640 * 8 B
  float* tabs = (float*)(ws + 6144);         // 40 floats
  size_t off = 8192;
  u16* xb    = (u16*)(ws + off); off += (size_t)MROWS * D_MODEL * 2;
  u16* wqkvs = (u16*)(ws + off); off += (size_t)NQKV * D_MODEL * 2;
  u16* wos   = (u16*)(ws + off); off += (size_t)D_MODEL * D_MODEL * 2;
  u16* qkvb  = (u16*)(ws + off); off += (size_t)MROWS * NQKV * 2;
  u16* ao    = (u16*)(ws + off); off += (size_t)MROWS * D_MODEL * 2;

  // 1. fused prep: weight signs + |w| partials + x->bf16
  prep_all<<<1152, 256, 0, stream>>>(wq, wk, wv, wo, x, wqkvs, wos, xb, partials);
  finalize_scales<<<1, 64, 0, stream>>>(partials, tabs);

  // 2. fused QKV projection (N = 3072; Q cols pre-scaled by sm_scale*log2e)
  gemm_bt<1><<<dim3(NQKV / 128, MROWS / 128), 256, 0, stream>>>(
      xb, wqkvs, qkvb, tabs, MROWS, NQKV, D_MODEL);

  // 3. GQA causal flash attention (paired, balanced, 2 blocks/CU)
  flash_attn<<<dim3(8, 64), 256, 0, stream>>>(qkvb, ao);

  // 4. output projection (f32 out)
  gemm_bt<0><<<dim3(D_MODEL / 128, MROWS / 128), 256, 0, stream>>>(
      ao, wos, out, tabs + 24, MROWS, D_MODEL, D_MODEL);
}

// Round 6
// 206.631 us; speedup vs baseline: 1.2965x; 1.0365x over previous
//
#include <hip/hip_runtime.h>
#include <stdint.h>

// ---------------------------------------------------------------------------
// BitAttention round 6:
//   - flash_attn v6: swapped QK^T (S^T fragments) -> lane-local q rows:
//     2-shfl reductions, cvt_pk+ds_write_b64 P-writes, 4-shfl alpha/l
//     redistribution; V staged as V^T via global_load_lds (XOR-swizzled,
//     dbuf) -- write_v/load_v deleted.
//   - gemm_bt<,VSPLIT>: V-column blocks store transposed into VT[512][4096]
//   - paired grid, defer-max, lazy l, Q pre-scaled by sm_scale*log2e (kept)
// ws layout (bytes):
//   [0,5120)    double partials[640]
//   [6144,6304) float tabs[40]
//   [8192,...)  xb(16M) wqkvs(12M) wos(8M) qkvb(24M) ao(16M) vt(4M)
// ---------------------------------------------------------------------------

#define D_MODEL 2048
#define S_LEN   2048
#define BATCH   2
#define NKV     8
#define HD      64
#define MROWS   (BATCH * S_LEN)   // 4096
#define NQKV    3072
#define LDQKV   3072

typedef unsigned short u16;
typedef __bf16 bf16x8 __attribute__((ext_vector_type(8)));
typedef float  f32x4  __attribute__((ext_vector_type(4)));

__device__ __forceinline__ u16 f2bf(float f) {
  union { float f; unsigned u; } v; v.f = f;
  unsigned r = v.u + 0x7FFFu + ((v.u >> 16) & 1u);   // RNE
  return (u16)(r >> 16);
}

__device__ __forceinline__ float exp2_fast(float x) {
  float r; asm("v_exp_f32 %0, %1" : "=v"(r) : "v"(x)); return r;
}

__device__ __forceinline__ unsigned cvt_pk_bf16(float a, float b) {
  unsigned r;
  asm("v_cvt_pk_bf16_f32 %0, %1, %2" : "=v"(r) : "v"(a), "v"(b));
  return r;
}

__device__ __forceinline__ void lds_load16(u16* lds, const u16* g) {
  __builtin_amdgcn_global_load_lds(
      (const __attribute__((address_space(1))) void*)g,
      (__attribute__((address_space(3))) void*)lds, 16, 0, 0);
}

#define SM_LOG2E 0.180336880f   // (1/sqrt(64)) * log2(e); folded into Q cols
#define THR_LOG2 11.5415603f    // 8 * log2(e)

// ---------------- fused prep: weight sign+|w| partials, x->bf16 ----------------
__global__ void prep_all(const float* __restrict__ wq, const float* __restrict__ wk,
                         const float* __restrict__ wv, const float* __restrict__ wo,
                         const float* __restrict__ x,
                         u16* __restrict__ wqkvs, u16* __restrict__ wos,
                         u16* __restrict__ xb, double* __restrict__ partials) {
  const int bid = blockIdx.x;
  const float* src; u16* dst; int n4, rb, nb; bool sgn = true;
  if (bid < 256)      { src = wq; dst = wqkvs;                  n4 = 1048576; rb = bid;       nb = 256; }
  else if (bid < 320) { src = wk; dst = wqkvs + 2048 * D_MODEL; n4 = 262144;  rb = bid - 256; nb = 64;  }
  else if (bid < 384) { src = wv; dst = wqkvs + 2560 * D_MODEL; n4 = 262144;  rb = bid - 320; nb = 64;  }
  else if (bid < 640) { src = wo; dst = wos;                    n4 = 1048576; rb = bid - 384; nb = 256; }
  else                { src = x;  dst = xb;                     n4 = 2097152; rb = bid - 640; nb = 512; sgn = false; }

  if (sgn) {
    double s = 0.0;
    for (int i = rb * 256 + threadIdx.x; i < n4; i += nb * 256) {
      float4 v = reinterpret_cast<const float4*>(src)[i];
      ushort4 o;
      o.x = v.x > 0.f ? 0x3F80 : (v.x < 0.f ? 0xBF80 : 0);
      o.y = v.y > 0.f ? 0x3F80 : (v.y < 0.f ? 0xBF80 : 0);
      o.z = v.z > 0.f ? 0x3F80 : (v.z < 0.f ? 0xBF80 : 0);
      o.w = v.w > 0.f ? 0x3F80 : (v.w < 0.f ? 0xBF80 : 0);
      reinterpret_cast<ushort4*>(dst)[i] = o;
      s += (double)fabsf(v.x) + (double)fabsf(v.y) +
           (double)fabsf(v.z) + (double)fabsf(v.w);
    }
    __shared__ double sm[256];
    sm[threadIdx.x] = s;
    __syncthreads();
    for (int off = 128; off > 0; off >>= 1) {
      if (threadIdx.x < off) sm[threadIdx.x] += sm[threadIdx.x + off];
      __syncthreads();
    }
    if (threadIdx.x == 0) partials[bid] = sm[0];
  } else {
    for (int i = rb * 256 + threadIdx.x; i < n4; i += nb * 256) {
      float4 v = reinterpret_cast<const float4*>(src)[i];
      ushort4 o;
      o.x = f2bf(v.x); o.y = f2bf(v.y); o.z = f2bf(v.z); o.w = f2bf(v.w);
      reinterpret_cast<ushort4*>(dst)[i] = o;
    }
  }
}

__global__ void finalize_scales(const double* __restrict__ partials,
                                float* __restrict__ tabs) {
  if (threadIdx.x == 0 && blockIdx.x == 0) {
    const int beg[4] = {0, 256, 320, 384};
    const int end[4] = {256, 320, 384, 640};
    const double counts[4] = {4194304.0, 1048576.0, 1048576.0, 4194304.0};
    float sc[4];
    for (int w = 0; w < 4; ++w) {
      double s = 0.0;
      for (int i = beg[w]; i < end[w]; ++i) s += partials[i];
      sc[w] = fmaxf((float)(s / counts[w]), 1e-5f);
    }
    for (int i = 0; i < 24; ++i)
      tabs[i] = (i < 16) ? sc[0] * SM_LOG2E : (i < 20 ? sc[1] : sc[2]);
    for (int i = 0; i < 16; ++i) tabs[24 + i] = sc[3];
  }
}

// ---------------- GEMM: C[m,n] = tab[bx] * sum_k A[m,k]*Bt[n,k] ----------------
// VSPLIT: blocks with bx>=20 (V columns) store TRANSPOSED into vt[512][4096].
template <int OUT_BF16, int VSPLIT>
__global__ __launch_bounds__(256, 2) void gemm_bt(
    const u16* __restrict__ A, const u16* __restrict__ Bt, void* __restrict__ Cv,
    const float* __restrict__ tab, u16* __restrict__ vt, int M, int N, int K) {
  __shared__ u16 lA[128 * 64];
  __shared__ u16 lB[128 * 64];
  const int tid = threadIdx.x;
  const int lane = tid & 63, wave = tid >> 6;
  const int lo = lane & 15, hi = lane >> 4;
  const int m0 = blockIdx.y * 128, n0 = blockIdx.x * 128;
  const int wr = (wave >> 1) * 64, wc = (wave & 1) * 64;

  f32x4 acc[4][4] = {};

  for (int k0 = 0; k0 < K; k0 += 64) {
#pragma unroll
    for (int it = 0; it < 4; ++it) {
      const int c = it * 256 + wave * 64 + lane;
      const int row = c >> 3, kc = (c & 7) << 3;
      lds_load16(&lA[(it * 256 + wave * 64) * 8], &A[(size_t)(m0 + row) * K + k0 + kc]);
      lds_load16(&lB[(it * 256 + wave * 64) * 8], &Bt[(size_t)(n0 + row) * K + k0 + kc]);
    }
    __syncthreads();
#pragma unroll
    for (int kk = 0; kk < 2; ++kk) {
      bf16x8 af[4], bfr[4];
#pragma unroll
      for (int i = 0; i < 4; ++i)
        af[i] = *reinterpret_cast<const bf16x8*>(&lA[(wr + i * 16 + lo) * 64 + kk * 32 + hi * 8]);
#pragma unroll
      for (int i = 0; i < 4; ++i)
        bfr[i] = *reinterpret_cast<const bf16x8*>(&lB[(wc + i * 16 + lo) * 64 + kk * 32 + hi * 8]);
#pragma unroll
      for (int mi = 0; mi < 4; ++mi)
#pragma unroll
        for (int ni = 0; ni < 4; ++ni)
          acc[mi][ni] = __builtin_amdgcn_mfma_f32_16x16x32_bf16(af[mi], bfr[ni], acc[mi][ni], 0, 0, 0);
    }
    __syncthreads();
  }

  const float scale = tab[blockIdx.x];
  if (VSPLIT && (int)blockIdx.x >= 20) {
    // V columns: transposed store, 4 consecutive rows (m) packed per dwordx2
#pragma unroll
    for (int mi = 0; mi < 4; ++mi) {
#pragma unroll
      for (int ni = 0; ni < 4; ++ni) {
        const int col = (n0 - 2560) + wc + ni * 16 + lo;       // 0..511
        const int row = m0 + wr + mi * 16 + hi * 4;            // mult of 4
        unsigned w01 = (unsigned)f2bf(acc[mi][ni][0] * scale) |
                       ((unsigned)f2bf(acc[mi][ni][1] * scale) << 16);
        unsigned w23 = (unsigned)f2bf(acc[mi][ni][2] * scale) |
                       ((unsigned)f2bf(acc[mi][ni][3] * scale) << 16);
        uint2 pk; pk.x = w01; pk.y = w23;
        *reinterpret_cast<uint2*>(vt + (size_t)col * MROWS + row) = pk;
      }
    }
    return;
  }
#pragma unroll
  for (int mi = 0; mi < 4; ++mi) {
#pragma unroll
    for (int ni = 0; ni < 4; ++ni) {
#pragma unroll
      for (int r = 0; r < 4; ++r) {
        const int row = m0 + wr + mi * 16 + hi * 4 + r;
        const int col = n0 + wc + ni * 16 + lo;
        const float v = acc[mi][ni][r] * scale;
        if (OUT_BF16)
          reinterpret_cast<u16*>(Cv)[(size_t)row * N + col] = f2bf(v);
        else
          reinterpret_cast<float*>(Cv)[(size_t)row * N + col] = v;
      }
    }
  }
}

// ---------------- flash attention v6 (GQA, causal, paired, S^T softmax) --------
__device__ __forceinline__ void stage_tile(u16* dst, const u16* base, int ld,
                                           int tid, int wave) {
#pragma unroll
  for (int it = 0; it < 2; ++it) {
    const int c = it * 256 + tid;
    const int row = c >> 3;
    const int ch = (c & 7) ^ (row & 7);   // pre-swizzled source (rule #21)
    lds_load16(dst + (it * 256 + wave * 64) * 8, base + (size_t)row * ld + ch * 8);
  }
}

__global__ __launch_bounds__(256, 2) void flash_attn(
    const u16* __restrict__ QKV, const u16* __restrict__ VT,
    u16* __restrict__ Og) {
  __shared__ u16 lK[2][64 * 64];    // [t][d], XOR-swizzled chunks
  __shared__ u16 lV[2][64 * 64];    // [d][t], XOR-swizzled chunks
  __shared__ u16 lP[4][32 * 72];    // per-wave P[q][t], stride 72

  const int tid = threadIdx.x;
  const int lane = tid & 63, wave = tid >> 6;
  const int lo = lane & 15, hi = lane >> 4;
  const int hy = blockIdx.y;
  const int b = hy >> 5, h = hy & 31, kv = h >> 2;
  const int brow = b * S_LEN;
  const u16* Q  = QKV + h * HD;
  const u16* Kb = QKV + 2048 + kv * HD;               // row stride LDQKV
  const u16* Vb = VT + (size_t)(kv * HD) * MROWS + brow;  // row d, stride MROWS
  const int swl = (lo & 7) << 3;
  const int xbase = (lane & 48) | ((lane >> 2) & 12); // lane with lo = hi*4 (+r)

#pragma unroll 1
  for (int pi = 0; pi < 2; ++pi) {
    const int qt = pi == 0 ? (int)blockIdx.x : (15 - (int)blockIdx.x);
    const int q0 = qt * 128;
    const int q0w = q0 + wave * 32;
    const int nt = 2 * qt + 2;

    // Q fragments resident for the pass (pre-scaled by sm_scale*log2e)
    bf16x8 qf[2][2];
#pragma unroll
    for (int mi = 0; mi < 2; ++mi) {
      const size_t qr = (size_t)(brow + q0w + mi * 16 + lo) * LDQKV;
#pragma unroll
      for (int kk = 0; kk < 2; ++kk)
        qf[mi][kk] = *reinterpret_cast<const bf16x8*>(&Q[qr + kk * 32 + hi * 8]);
    }

    f32x4 oacc[2][4] = {};
    float m_run[2] = {-1e30f, -1e30f};
    float l_lane[2] = {0.f, 0.f};

    // prologue: stage tile 0 into buffer 0
    stage_tile(lK[0], Kb + (size_t)brow * LDQKV, LDQKV, tid, wave);
    stage_tile(lV[0], Vb, MROWS, tid, wave);
    __syncthreads();

#pragma unroll 1
    for (int ti = 0; ti < nt; ++ti) {
      const int t0 = ti * 64;
      const int cur = ti & 1;
      u16* lKc = (u16*)lK[cur];
      u16* lVc = (u16*)lV[cur];

      // ---- S^T = K Q^T : C[t][q]; lane holds q=lo, t = nf*16 + hi*4 + r ----
      f32x4 sacc[2][4] = {};
      __builtin_amdgcn_s_setprio(1);
#pragma unroll
      for (int kk = 0; kk < 2; ++kk) {
#pragma unroll
        for (int nf = 0; nf < 4; ++nf) {
          bf16x8 kf = *reinterpret_cast<const bf16x8*>(
              &lKc[(nf * 16 + lo) * 64 + ((kk * 32 + hi * 8) ^ swl)]);
#pragma unroll
          for (int mi = 0; mi < 2; ++mi)
            sacc[mi][nf] = __builtin_amdgcn_mfma_f32_16x16x32_bf16(
                kf, qf[mi][kk], sacc[mi][nf], 0, 0, 0);
        }
      }
      __builtin_amdgcn_s_setprio(0);

      // ---- prefetch next tile (K and V^T direct to LDS) ----
      const bool has_next = (ti + 1 < nt);
      if (has_next) {
        stage_tile(lK[cur ^ 1], Kb + (size_t)(brow + t0 + 64) * LDQKV, LDQKV, tid, wave);
        stage_tile(lV[cur ^ 1], Vb + t0 + 64, MROWS, tid, wave);
      }

      // ---- mask + per-lane max over own 16 t-values, then 2-shfl row max ----
      const bool full = (t0 + 64 <= q0);
      float sv[2][4][4];
      float rowmax[2];
      bool ok = true;
#pragma unroll
      for (int mi = 0; mi < 2; ++mi) {
        const int qg = q0w + mi * 16 + lo;
        float mt = -1e30f;
#pragma unroll
        for (int nf = 0; nf < 4; ++nf) {
#pragma unroll
          for (int r = 0; r < 4; ++r) {
            float s = sacc[mi][nf][r];
            if (!full) {
              const int tg = t0 + nf * 16 + hi * 4 + r;
              if (tg > qg) s = -1e30f;
            }
            sv[mi][nf][r] = s;
            mt = fmaxf(mt, s);
          }
        }
        mt = fmaxf(mt, __shfl_xor(mt, 16));
        mt = fmaxf(mt, __shfl_xor(mt, 32));
        rowmax[mi] = mt;
        ok = ok && (mt <= m_run[mi] + THR_LOG2);
      }

      // ---- defer-max: rescale only when a row max grew (T13) ----
      if (!__all((int)ok)) {
#pragma unroll
        for (int mi = 0; mi < 2; ++mi) {
          const float mn = fmaxf(m_run[mi], rowmax[mi]);
          const float alpha = exp2_fast(m_run[mi] - mn);
          m_run[mi] = mn;
          l_lane[mi] *= alpha;
          const float a0 = __shfl(alpha, xbase + 0);
          const float a1 = __shfl(alpha, xbase + 1);
          const float a2 = __shfl(alpha, xbase + 2);
          const float a3 = __shfl(alpha, xbase + 3);
#pragma unroll
          for (int nf = 0; nf < 4; ++nf) {
            oacc[mi][nf][0] *= a0; oacc[mi][nf][1] *= a1;
            oacc[mi][nf][2] *= a2; oacc[mi][nf][3] *= a3;
          }
        }
      }

      // ---- exp2 + packed P write (cvt_pk + ds_write_b64) + lane-partial l ----
#pragma unroll
      for (int mi = 0; mi < 2; ++mi) {
        u16* lprow = &lP[wave][(mi * 16 + lo) * 72 + hi * 4];
        float ls = 0.f;
#pragma unroll
        for (int nf = 0; nf < 4; ++nf) {
          const float e0 = exp2_fast(sv[mi][nf][0] - m_run[mi]);
          const float e1 = exp2_fast(sv[mi][nf][1] - m_run[mi]);
          const float e2 = exp2_fast(sv[mi][nf][2] - m_run[mi]);
          const float e3 = exp2_fast(sv[mi][nf][3] - m_run[mi]);
          ls += (e0 + e1) + (e2 + e3);
          uint2 pk; pk.x = cvt_pk_bf16(e0, e1); pk.y = cvt_pk_bf16(e2, e3);
          *reinterpret_cast<uint2*>(lprow + nf * 16) = pk;
        }
        l_lane[mi] += ls;
      }

      // ---- O += P V ----
      __builtin_amdgcn_s_setprio(1);
#pragma unroll
      for (int kk = 0; kk < 2; ++kk) {
        bf16x8 pf[2];
#pragma unroll
        for (int mi = 0; mi < 2; ++mi)
          pf[mi] = *reinterpret_cast<const bf16x8*>(
              &lP[wave][(mi * 16 + lo) * 72 + kk * 32 + hi * 8]);
#pragma unroll
        for (int nf = 0; nf < 4; ++nf) {
          bf16x8 vf = *reinterpret_cast<const bf16x8*>(
              &lVc[(nf * 16 + lo) * 64 + ((kk * 32 + hi * 8) ^ swl)]);
#pragma unroll
          for (int mi = 0; mi < 2; ++mi)
            oacc[mi][nf] = __builtin_amdgcn_mfma_f32_16x16x32_bf16(
                pf[mi], vf, oacc[mi][nf], 0, 0, 0);
        }
      }
      __builtin_amdgcn_s_setprio(0);
      __syncthreads();   // all reads of cur done before it becomes the stage target
    }

    // ---- epilogue: finish l across hi-group, redistribute, store ----
#pragma unroll
    for (int mi = 0; mi < 2; ++mi) {
      float ls = l_lane[mi];
      ls += __shfl_xor(ls, 16);
      ls += __shfl_xor(ls, 32);
      const float inv = 1.f / ls;
      const float i0 = __shfl(inv, xbase + 0);
      const float i1 = __shfl(inv, xbase + 1);
      const float i2 = __shfl(inv, xbase + 2);
      const float i3 = __shfl(inv, xbase + 3);
#pragma unroll
      for (int nf = 0; nf < 4; ++nf) {
        const size_t rb0 = (size_t)(brow + q0w + mi * 16 + hi * 4) * D_MODEL +
                           h * HD + nf * 16 + lo;
        Og[rb0 + 0 * D_MODEL] = f2bf(oacc[mi][nf][0] * i0);
        Og[rb0 + 1 * D_MODEL] = f2bf(oacc[mi][nf][1] * i1);
        Og[rb0 + 2 * D_MODEL] = f2bf(oacc[mi][nf][2] * i2);
        Og[rb0 + 3 * D_MODEL] = f2bf(oacc[mi][nf][3] * i3);
      }
    }
  }
}

// ---------------- launcher ----------------
extern "C" void kernel_launch(void* const* d_in, const int* in_sizes, int n_in,
                              void* d_out, int out_size, void* d_ws, size_t ws_size,
                              hipStream_t stream) {
  (void)in_sizes; (void)n_in; (void)out_size; (void)ws_size;
  const float* x  = (const float*)d_in[0];
  const float* wq = (const float*)d_in[1];
  const float* wk = (const float*)d_in[2];
  const float* wv = (const float*)d_in[3];
  const float* wo = (const float*)d_in[4];
  float* out = (float*)d_out;
  char* ws = (char*)d_ws;

  double* partials = (double*)ws;            // 640 * 8 B
  float* tabs = (float*)(ws + 6144);         // 40 floats
  size_t off = 8192;
  u16* xb    = (u16*)(ws + off); off += (size_t)MROWS * D_MODEL * 2;
  u16* wqkvs = (u16*)(ws + off); off += (size_t)NQKV * D_MODEL * 2;
  u16* wos   = (u16*)(ws + off); off += (size_t)D_MODEL * D_MODEL * 2;
  u16* qkvb  = (u16*)(ws + off); off += (size_t)MROWS * NQKV * 2;
  u16* ao    = (u16*)(ws + off); off += (size_t)MROWS * D_MODEL * 2;
  u16* vt    = (u16*)(ws + off); off += (size_t)512 * MROWS * 2;

  // 1. fused prep: weight signs + |w| partials + x->bf16
  prep_all<<<1152, 256, 0, stream>>>(wq, wk, wv, wo, x, wqkvs, wos, xb, partials);
  finalize_scales<<<1, 64, 0, stream>>>(partials, tabs);

  // 2. fused QKV projection; V columns stored transposed into vt
  gemm_bt<1, 1><<<dim3(NQKV / 128, MROWS / 128), 256, 0, stream>>>(
      xb, wqkvs, qkvb, tabs, vt, MROWS, NQKV, D_MODEL);

  // 3. GQA causal flash attention (paired, S^T softmax, V^T staging)
  flash_attn<<<dim3(8, 64), 256, 0, stream>>>(qkvb, vt, ao);

  // 4. output projection (f32 out)
  gemm_bt<0, 0><<<dim3(D_MODEL / 128, MROWS / 128), 256, 0, stream>>>(
      ao, wos, out, tabs + 24, nullptr, MROWS, D_MODEL, D_MODEL);
}